// Round 8
// baseline (271.372 us; speedup 1.0000x reference)
//
#include <hip/hip_runtime.h>
#include <hip/hip_bf16.h>
#include <stdint.h>

// B=2, L=S=2048, D_MODEL=1024, H=16, E=64. Inputs/outputs fp32; intermediates bf16.
#define BATCH 2
#define SEQ   2048
#define DM    1024
#define NH    16
#define EH    64
#define MROWS (BATCH*SEQ)   // 4096

typedef __attribute__((ext_vector_type(8))) short  short8;   // MFMA A/B frag (8 bf16)
typedef __attribute__((ext_vector_type(4))) float  floatx4;  // MFMA C/D frag
typedef __attribute__((ext_vector_type(8))) unsigned short ushort8v;
typedef __attribute__((ext_vector_type(4))) unsigned short ushort4v;

// Half-up rounding (2 VALU): differs from RNE only on exact 0x8000 ties (p~2^-16).
__device__ __forceinline__ unsigned short f2bf(float f) {
    return (unsigned short)((__float_as_uint(f) + 0x8000u) >> 16);
}

__device__ __forceinline__ void gload_lds16(const void* g, void* l) {
    // async global->LDS, 16B/lane; LDS dest = wave-uniform base + lane*16
    __builtin_amdgcn_global_load_lds(
        (const __attribute__((address_space(1))) unsigned int*)g,
        (__attribute__((address_space(3))) unsigned int*)l, 16, 0, 0);
}

// ---------------------------------------------------------------------------
// Transpose+convert: W [K][N] fp32 -> WT [N][K] bf16. 32x32 LDS tiles.
// ---------------------------------------------------------------------------
__global__ __launch_bounds__(256)
void transpose_w(const float* __restrict__ W0, const float* __restrict__ W1,
                 const float* __restrict__ W2, const float* __restrict__ W3,
                 unsigned short* __restrict__ T0, unsigned short* __restrict__ T1,
                 unsigned short* __restrict__ T2, unsigned short* __restrict__ T3,
                 int zbase)
{
    int z = zbase + blockIdx.z;
    const float* W = (z == 0) ? W0 : (z == 1) ? W1 : (z == 2) ? W2 : W3;
    unsigned short* T = (z == 0) ? T0 : (z == 1) ? T1 : (z == 2) ? T2 : T3;
    __shared__ float t[32][33];
    const int tid = threadIdx.x;
    const int k0 = blockIdx.y * 32, n0 = blockIdx.x * 32;
    {
        int r = tid >> 3, c4 = (tid & 7) * 4;
        float4 u = *(const float4*)&W[(size_t)(k0 + r) * DM + n0 + c4];
        t[r][c4 + 0] = u.x; t[r][c4 + 1] = u.y; t[r][c4 + 2] = u.z; t[r][c4 + 3] = u.w;
    }
    __syncthreads();
    {
        int n = tid >> 3, k4 = (tid & 7) * 4;
        ushort4v o;
        o[0] = f2bf(t[k4 + 0][n]); o[1] = f2bf(t[k4 + 1][n]);
        o[2] = f2bf(t[k4 + 2][n]); o[3] = f2bf(t[k4 + 3][n]);
        *(ushort4v*)&T[(size_t)(n0 + n) * DM + k0 + k4] = o;
    }
}

// ---------------------------------------------------------------------------
// Fused Q/K/V projection — r9 phase structure with COUNTED barrier waits (T4).
// r16 counters: MfmaUtil 15%, VALUBusy 18%, HBM 15%, ~1550cy/iter -> the two
// __syncthreads vmcnt(0) drains are ~1200cy of it: B1 drained the act fp32
// prefetch issued one MFMA-phase earlier (~700cy exposed HBM lat); B2 drained
// weight gload_lds issued one cvt earlier.
// Fix, keeping LDS single-buffered + identical phase structure:
//  * B1 = raw s_barrier (all ds_reads consumed by MFMAs before it; in-flight
//    act VGPR loads touch no LDS -> no alias hazard, unlike r10's dbuf).
//  * B2 = s_waitcnt vmcnt(4) lgkmcnt(0) + raw s_barrier: retires weight
//    gload_lds + older preloads, leaves the 4 newest (this phase's act
//    prefetch) in flight ACROSS barriers.
//  * act prefetch 2 tiles deep (preA/preB, named regs, 2x-unrolled loop,
//    rule #20); ~1.5-phase (>1200cy) latency cover.
//  * stageW issued before cvt so cvt VALU covers L2 latency of weights.
// Tail phases (no preload) wait vmcnt(0). sched_barrier(0) after each
// barrier per rule #18.
// ---------------------------------------------------------------------------
struct ProjArgs {
    const float* act[3];            // queries, keys, values
    const unsigned short* wt[3];    // WqT, WkT, WvT
    const float* bias[3];
    unsigned short* C[3];           // Qh, Kh, Vt
    float oscale[3];
};

__global__ __launch_bounds__(256)
void proj_qkv(ProjArgs pa)
{
    const int z = blockIdx.z;
    const bool vt = (z == 2);
    const int linear = (int)(blockIdx.x + gridDim.x * blockIdx.y);  // 0..255
    int rb, cb;
    if (!vt) { rb = linear & 31; cb = linear >> 5; }   // pin activation row-tile
    else     { cb = linear & 31; rb = linear >> 5; }   // pin values tile
    const int row0 = rb * 128, col0 = cb * 128;

    const float* act = pa.act[z];
    const unsigned short* wt = pa.wt[z];
    const int actBase = vt ? col0 : row0;   // act rows staged (fp32 -> cvt)
    const int wtBase  = vt ? row0 : col0;   // weight rows staged (async bf16)

    __shared__ unsigned short As[128 * 32];  // [row][32], 64B rows
    __shared__ unsigned short Bs[128 * 32];
    unsigned short* convDst  = vt ? Bs : As;
    unsigned short* asyncDst = vt ? As : Bs;

    const int tid = threadIdx.x;
    const int lane = tid & 63, w = tid >> 6;
    const int lane15 = lane & 15, quad = lane >> 4;

    floatx4 acc[2][8] = {};

    const int arow = tid >> 2;            // act row (and +64)
    const int acol = (tid & 3) * 8;
    // swizzled chunk slot for cvt rows (same for both rr: (64>>1)&3 == 0)
    const int cp = (tid & 3) ^ ((arow >> 1) & 3);
    const int sw = (lane15 >> 1) & 3;

    float4 preA[4], preB[4];

    auto loadPre = [&](float4 (&pre)[4], int kt) {
        const float* p0 = &act[(size_t)(actBase + arow) * DM + kt + acol];
        const float* p1 = &act[(size_t)(actBase + 64 + arow) * DM + kt + acol];
        pre[0] = *(const float4*)p0; pre[1] = *(const float4*)(p0 + 4);
        pre[2] = *(const float4*)p1; pre[3] = *(const float4*)(p1 + 4);
    };
    auto cvtStore = [&](const float4 (&pre)[4]) {
#pragma unroll
        for (int rr = 0; rr < 2; ++rr) {
            int row = rr * 64 + arow;
            ushort8v o8;
            float4 u0 = pre[rr * 2], u1 = pre[rr * 2 + 1];
            o8[0] = f2bf(u0.x); o8[1] = f2bf(u0.y); o8[2] = f2bf(u0.z); o8[3] = f2bf(u0.w);
            o8[4] = f2bf(u1.x); o8[5] = f2bf(u1.y); o8[6] = f2bf(u1.z); o8[7] = f2bf(u1.w);
            *(ushort8v*)&convDst[(size_t)(row * 4 + cp) * 8] = o8;
        }
    };
    auto stageW = [&](int kt) {
#pragma unroll
        for (int rr = 0; rr < 2; ++rr) {
            int c = rr * 256 + w * 64 + lane;
            int row = c >> 2;
            int gch = (c & 3) ^ ((row >> 1) & 3);
            gload_lds16(&wt[(size_t)(wtBase + row) * DM + kt + gch * 8],
                        (char*)asyncDst + (size_t)(rr * 256 + w * 64) * 16);
        }
    };
    auto mfmaPhase = [&]() {
        short8 af[2], bf[8];
#pragma unroll
        for (int i = 0; i < 2; ++i)
            af[i] = *(const short8*)&As[(w * 32 + i * 16 + lane15) * 32 + ((quad ^ sw) << 3)];
#pragma unroll
        for (int j = 0; j < 8; ++j)
            bf[j] = *(const short8*)&Bs[(j * 16 + lane15) * 32 + ((quad ^ sw) << 3)];
#pragma unroll
        for (int i = 0; i < 2; ++i)
#pragma unroll
            for (int j = 0; j < 8; ++j)
                acc[i][j] = __builtin_amdgcn_mfma_f32_16x16x32_bf16(af[i], bf[j], acc[i][j], 0, 0, 0);
    };

    loadPre(preA, 0);
    loadPre(preB, 32);

    for (int kt = 0; kt < DM; kt += 64) {
        // ---- phase A: tile kt (regs preA) ----
        __builtin_amdgcn_s_barrier();            // B1: prev frag reads done
        __builtin_amdgcn_sched_barrier(0);
        stageW(kt);
        cvtStore(preA);
        if (kt + 64 < DM) {
            loadPre(preA, kt + 64);              // stays in flight across B2
            asm volatile("s_waitcnt vmcnt(4) lgkmcnt(0)" ::: "memory");
        } else {
            asm volatile("s_waitcnt vmcnt(0) lgkmcnt(0)" ::: "memory");
        }
        __builtin_amdgcn_s_barrier();            // B2: weights + cvt visible
        __builtin_amdgcn_sched_barrier(0);
        mfmaPhase();

        // ---- phase B: tile kt+32 (regs preB) ----
        __builtin_amdgcn_s_barrier();
        __builtin_amdgcn_sched_barrier(0);
        stageW(kt + 32);
        cvtStore(preB);
        if (kt + 96 < DM) {
            loadPre(preB, kt + 96);
            asm volatile("s_waitcnt vmcnt(4) lgkmcnt(0)" ::: "memory");
        } else {
            asm volatile("s_waitcnt vmcnt(0) lgkmcnt(0)" ::: "memory");
        }
        __builtin_amdgcn_s_barrier();
        __builtin_amdgcn_sched_barrier(0);
        mfmaPhase();
    }

    const float* bias = pa.bias[z];
    const float os = pa.oscale[z];
    unsigned short* C = pa.C[z];
#pragma unroll
    for (int i = 0; i < 2; ++i) {
#pragma unroll
        for (int j = 0; j < 8; ++j) {
#pragma unroll
            for (int r = 0; r < 4; ++r) {
                int row = row0 + w * 32 + i * 16 + quad * 4 + r;
                int col = col0 + j * 16 + lane15;
                if (!vt) {
                    float v = (acc[i][j][r] + bias[col]) * os;
                    int b = row >> 11, l = row & (SEQ - 1);
                    int h = col >> 6,  e = col & (EH - 1);
                    C[((size_t)(b * NH + h) * SEQ + l) * EH + e] = f2bf(v);
                } else {
                    float v = acc[i][j][r] + bias[row];       // bias by e-row
                    int h = row >> 6,  e = row & (EH - 1);
                    int b = col >> 11, l = col & (SEQ - 1);
                    C[((size_t)(b * NH + h) * EH + e) * SEQ + l] = f2bf(v);
                }
            }
        }
    }
}

// ---------------------------------------------------------------------------
// Output projection — r9 structure + swizzle (unchanged this round).
// Tile 128x64 (NT=4), BK=32, grid (16,32), both operands async bf16.
// ---------------------------------------------------------------------------
__global__ __launch_bounds__(256)
void gemm_out(const unsigned short* __restrict__ ctx,
              const unsigned short* __restrict__ WoT,
              const float* __restrict__ bo,
              float* __restrict__ out)
{
    const int linear = (int)(blockIdx.x + gridDim.x * blockIdx.y);  // 0..511
    const int rb = linear & 31, cb = linear >> 5;                   // cb 0..15
    const int row0 = rb * 128, col0 = cb * 64;

    __shared__ unsigned short As[128 * 32];
    __shared__ unsigned short Bs[64 * 32];

    const int tid = threadIdx.x;
    const int lane = tid & 63, w = tid >> 6;
    const int lane15 = lane & 15, quad = lane >> 4;
    const int sw = (lane15 >> 1) & 3;

    floatx4 acc[2][4] = {};

    for (int kt = 0; kt < DM; kt += 32) {
        __syncthreads();
#pragma unroll
        for (int rr = 0; rr < 2; ++rr) {
            int c = rr * 256 + w * 64 + lane;
            int row = c >> 2;
            int gch = (c & 3) ^ ((row >> 1) & 3);
            gload_lds16(&ctx[(size_t)(row0 + row) * DM + kt + gch * 8],
                        (char*)As + (size_t)(rr * 256 + w * 64) * 16);
        }
        {
            int c = w * 64 + lane;                 // 256 chunks
            int row = c >> 2;
            int gch = (c & 3) ^ ((row >> 1) & 3);
            gload_lds16(&WoT[(size_t)(col0 + row) * DM + kt + gch * 8],
                        (char*)Bs + (size_t)(w * 64) * 16);
        }
        __syncthreads();

        short8 af[2], bf[4];
#pragma unroll
        for (int i = 0; i < 2; ++i)
            af[i] = *(const short8*)&As[(w * 32 + i * 16 + lane15) * 32 + ((quad ^ sw) << 3)];
#pragma unroll
        for (int j = 0; j < 4; ++j)
            bf[j] = *(const short8*)&Bs[(j * 16 + lane15) * 32 + ((quad ^ sw) << 3)];
#pragma unroll
        for (int i = 0; i < 2; ++i)
#pragma unroll
            for (int j = 0; j < 4; ++j)
                acc[i][j] = __builtin_amdgcn_mfma_f32_16x16x32_bf16(af[i], bf[j], acc[i][j], 0, 0, 0);
    }

#pragma unroll
    for (int i = 0; i < 2; ++i)
#pragma unroll
        for (int j = 0; j < 4; ++j)
#pragma unroll
            for (int r = 0; r < 4; ++r) {
                int row = row0 + w * 32 + i * 16 + quad * 4 + r;
                int col = col0 + j * 16 + lane15;
                out[(size_t)row * DM + col] = acc[i][j][r] + bo[col];
            }
}

// ---------------------------------------------------------------------------
// MFMA flash attention — r0 structure + Ps XOR-swizzle (r16, passed; neutral
// on time but conflict-free and 2KB less LDS). Unchanged this round.
// ---------------------------------------------------------------------------
__device__ __forceinline__ void stage_kv(const unsigned short* __restrict__ Kp,
                                         const unsigned short* __restrict__ Vp,
                                         int st, unsigned short* ksb, unsigned short* vsb,
                                         int w, int lane)
{
#pragma unroll
    for (int rr = 0; rr < 2; ++rr) {
        int p = rr * 256 + w * 64 + lane;      // LDS chunk position
        int row = p >> 3;
        int gch = (p & 7) ^ (row & 7);         // swizzled source chunk
        gload_lds16(&Kp[(size_t)(st + row) * EH + gch * 8],
                    ksb + (size_t)(rr * 256 + w * 64) * 8);
        gload_lds16(&Vp[(size_t)row * SEQ + st + gch * 8],
                    vsb + (size_t)(rr * 256 + w * 64) * 8);
    }
}

__global__ __launch_bounds__(256)
void attn_mfma(const unsigned short* __restrict__ Qh,
               const unsigned short* __restrict__ Kh,
               const unsigned short* __restrict__ Vt,
               unsigned short* __restrict__ ctx)
{
    __shared__ unsigned short Ks[2][64 * 64];   // swizzled [s][e]
    __shared__ unsigned short Vs[2][64 * 64];   // swizzled [e][s]
    __shared__ unsigned short Ps[128][64];      // [q_local][s], XOR-swizzled

    const int tid = threadIdx.x;
    const int lane = tid & 63, w = tid >> 6;
    const int lane15 = lane & 15, quad = lane >> 4;

    // (b,h)-pinned swizzle: linear%8 == bh%8 -> one XCD per 4 bh sets
    const int linear = (int)(blockIdx.x + 16 * (blockIdx.y + 16 * blockIdx.z));
    const int bhid = linear & 31;      // 0..31
    const int qt = linear >> 5;        // 0..15
    const int h = bhid & 15, b = bhid >> 4;

    const size_t bh = (size_t)(b * NH + h);
    const unsigned short* Kp = Kh + bh * SEQ * EH;
    const unsigned short* Vp = Vt + bh * EH * SEQ;

    short8 qf[2][2];
    {
        const unsigned short* Qp =
            Qh + (bh * SEQ + (size_t)qt * 128 + w * 32 + lane15) * EH;
#pragma unroll
        for (int ks = 0; ks < 2; ++ks) {
            qf[0][ks] = *(const short8*)(Qp + ks * 32 + quad * 8);
            qf[1][ks] = *(const short8*)(Qp + 16 * EH + ks * 32 + quad * 8);
        }
    }
    short8 ones;
#pragma unroll
    for (int i = 0; i < 8; ++i) ones[i] = (short)0x3F80;   // bf16 1.0

    floatx4 o[2][4] = {};
    floatx4 lacc[2] = {};

    stage_kv(Kp, Vp, 0, Ks[0], Vs[0], w, lane);
    __syncthreads();
    int cur = 0;

    for (int st = 0; st < SEQ; st += 64) {
        int nxt = cur ^ 1;
        if (st + 64 < SEQ)
            stage_kv(Kp, Vp, st + 64, Ks[nxt], Vs[nxt], w, lane);
        const unsigned short* ksb = Ks[cur];
        const unsigned short* vsb = Vs[cur];

        floatx4 sacc[4][2] = {};
#pragma unroll
        for (int ts = 0; ts < 4; ++ts) {
#pragma unroll
            for (int ks = 0; ks < 2; ++ks) {
                short8 kf = *(const short8*)&ksb[((ts * 16 + lane15) << 6) +
                                                 ((((ks << 2) + quad) ^ (lane15 & 7)) << 3)];
                sacc[ts][0] = __builtin_amdgcn_mfma_f32_16x16x32_bf16(kf, qf[0][ks], sacc[ts][0], 0, 0, 0);
                sacc[ts][1] = __builtin_amdgcn_mfma_f32_16x16x32_bf16(kf, qf[1][ks], sacc[ts][1], 0, 0, 0);
            }
        }

        // P = exp2(S'); pack 4 consecutive-s bf16 -> one 8B write per tile,
        // at XOR-swizzled chunk: phys = ((ts*2+(quad>>1)) ^ (row&7))*8 + (quad&1)*4
#pragma unroll
        for (int ts = 0; ts < 4; ++ts)
#pragma unroll
            for (int nq = 0; nq < 2; ++nq) {
                unsigned int u0 = __float_as_uint(__builtin_amdgcn_exp2f(sacc[ts][nq][0])) + 0x8000u;
                unsigned int u1 = __float_as_uint(__builtin_amdgcn_exp2f(sacc[ts][nq][1])) + 0x8000u;
                unsigned int u2 = __float_as_uint(__builtin_amdgcn_exp2f(sacc[ts][nq][2])) + 0x8000u;
                unsigned int u3 = __float_as_uint(__builtin_amdgcn_exp2f(sacc[ts][nq][3])) + 0x8000u;
                uint2 pk;
                pk.x = (u0 >> 16) | (u1 & 0xFFFF0000u);
                pk.y = (u2 >> 16) | (u3 & 0xFFFF0000u);
                *(uint2*)&Ps[w * 32 + nq * 16 + lane15]
                            [(((ts * 2 + (quad >> 1)) ^ (lane15 & 7)) << 3) + ((quad & 1) << 2)] = pk;
            }

        // O += P @ V ; l += P @ 1   (Ps rows wave-local: no barrier needed)
#pragma unroll
        for (int ks = 0; ks < 2; ++ks) {
            short8 pf[2];
#pragma unroll
            for (int mt = 0; mt < 2; ++mt) {
                pf[mt] = *(const short8*)&Ps[w * 32 + mt * 16 + lane15]
                                            [((((ks << 2) + quad) ^ (lane15 & 7)) << 3)];
                lacc[mt] = __builtin_amdgcn_mfma_f32_16x16x32_bf16(pf[mt], ones, lacc[mt], 0, 0, 0);
            }
#pragma unroll
            for (int t2 = 0; t2 < 4; ++t2) {
                short8 vf = *(const short8*)&vsb[((t2 * 16 + lane15) << 6) +
                                                 ((((ks << 2) + quad) ^ (lane15 & 7)) << 3)];
                o[0][t2] = __builtin_amdgcn_mfma_f32_16x16x32_bf16(pf[0], vf, o[0][t2], 0, 0, 0);
                o[1][t2] = __builtin_amdgcn_mfma_f32_16x16x32_bf16(pf[1], vf, o[1][t2], 0, 0, 0);
            }
        }
        __syncthreads();
        cur = nxt;
    }

#pragma unroll
    for (int mt = 0; mt < 2; ++mt) {
        float inv[4];
#pragma unroll
        for (int r = 0; r < 4; ++r) inv[r] = 1.0f / lacc[mt][r];
#pragma unroll
        for (int t2 = 0; t2 < 4; ++t2)
#pragma unroll
            for (int r = 0; r < 4; ++r) {
                int q = qt * 128 + w * 32 + mt * 16 + quad * 4 + r;
                int col = h * EH + t2 * 16 + lane15;
                ctx[((size_t)(b * SEQ + q)) * DM + col] = f2bf(o[mt][t2][r] * inv[r]);
            }
    }
}

extern "C" void kernel_launch(void* const* d_in, const int* in_sizes, int n_in,
                              void* d_out, int out_size, void* d_ws, size_t ws_size,
                              hipStream_t stream)
{
    const float* queries = (const float*)d_in[0];
    const float* keys    = (const float*)d_in[1];
    const float* values  = (const float*)d_in[2];
    const float* Wq = (const float*)d_in[3];
    const float* bq = (const float*)d_in[4];
    const float* Wk = (const float*)d_in[5];
    const float* bk = (const float*)d_in[6];
    const float* Wv = (const float*)d_in[7];
    const float* bv = (const float*)d_in[8];
    const float* Wo = (const float*)d_in[9];
    const float* bo = (const float*)d_in[10];
    float* out = (float*)d_out;

    // 32 MB workspace (ushort elems):
    //   [0,4M)   Qh    (WoT overlays after attn)
    //   [4M,8M)  Kh
    //   [8M,12M) Vt
    //   [12M,16M) ctx  (WqT/WkT/WvT live here until attn overwrites)
    unsigned short* ws = (unsigned short*)d_ws;
    const size_t MAT = (size_t)MROWS * DM;   // 4M elems
    const size_t WSZ = (size_t)DM * DM;      // 1M elems
    unsigned short* Qhp = ws;
    unsigned short* Khp = ws + MAT;
    unsigned short* Vtp = ws + 2 * MAT;
    unsigned short* ctx = ws + 3 * MAT;
    unsigned short* WqT = ctx;               // dead once attn writes ctx
    unsigned short* WkT = ctx + WSZ;
    unsigned short* WvT = ctx + 2 * WSZ;
    unsigned short* WoT = ws;                // overlays Qh after attn

    // 1/sqrt(EH) * log2(e): exp2(S') == exp(S/8)
    const float qscale = 0.125f * 1.44269504088896f;

    // 1. weight transposes Wq/Wk/Wv
    transpose_w<<<dim3(DM / 32, DM / 32, 3), 256, 0, stream>>>(
        Wq, Wk, Wv, Wo, WqT, WkT, WvT, WoT, 0);

    // 2. fused Q/K/V projections (counted-vmcnt barriers + 2-deep act prefetch)
    ProjArgs pa;
    pa.act[0] = queries; pa.act[1] = keys; pa.act[2] = values;
    pa.wt[0] = WqT;      pa.wt[1] = WkT;   pa.wt[2] = WvT;
    pa.bias[0] = bq;     pa.bias[1] = bk;  pa.bias[2] = bv;
    pa.C[0] = Qhp;       pa.C[1] = Khp;    pa.C[2] = Vtp;
    pa.oscale[0] = qscale; pa.oscale[1] = 1.f; pa.oscale[2] = 1.f;
    proj_qkv<<<dim3(8, 32, 3), 256, 0, stream>>>(pa);

    // 3. attention -> ctx
    attn_mfma<<<dim3(SEQ / 128, NH, BATCH), 256, 0, stream>>>(Qhp, Khp, Vtp, ctx);

    // 4. Wo transpose into dead Qh region
    transpose_w<<<dim3(DM / 32, DM / 32, 1), 256, 0, stream>>>(
        Wq, Wk, Wv, Wo, WqT, WkT, WvT, WoT, 3);

    // 5. output projection
    gemm_out<<<dim3(16, 32), 256, 0, stream>>>(ctx, WoT, bo, out);
}

// Round 10
// 238.566 us; speedup vs baseline: 1.1375x; 1.1375x over previous
//
#include <hip/hip_runtime.h>
#include <hip/hip_bf16.h>
#include <stdint.h>

// B=2, L=S=2048, D_MODEL=1024, H=16, E=64. Inputs/outputs fp32; intermediates bf16.
#define BATCH 2
#define SEQ   2048
#define DM    1024
#define NH    16
#define EH    64
#define MROWS (BATCH*SEQ)   // 4096

typedef __attribute__((ext_vector_type(8))) short  short8;   // MFMA A/B frag (8 bf16)
typedef __attribute__((ext_vector_type(4))) float  floatx4;  // MFMA C/D frag
typedef __attribute__((ext_vector_type(8))) unsigned short ushort8v;
typedef __attribute__((ext_vector_type(4))) unsigned short ushort4v;

// Half-up rounding (2 VALU): differs from RNE only on exact 0x8000 ties (p~2^-16).
__device__ __forceinline__ unsigned short f2bf(float f) {
    return (unsigned short)((__float_as_uint(f) + 0x8000u) >> 16);
}

__device__ __forceinline__ void gload_lds16(const void* g, void* l) {
    // async global->LDS, 16B/lane; LDS dest = wave-uniform base + lane*16
    __builtin_amdgcn_global_load_lds(
        (const __attribute__((address_space(1))) unsigned int*)g,
        (__attribute__((address_space(3))) unsigned int*)l, 16, 0, 0);
}

// ---------------------------------------------------------------------------
// Transpose+convert: W [K][N] fp32 -> WT [N][K] bf16. 32x32 LDS tiles.
// ---------------------------------------------------------------------------
__global__ __launch_bounds__(256)
void transpose_w(const float* __restrict__ W0, const float* __restrict__ W1,
                 const float* __restrict__ W2, const float* __restrict__ W3,
                 unsigned short* __restrict__ T0, unsigned short* __restrict__ T1,
                 unsigned short* __restrict__ T2, unsigned short* __restrict__ T3,
                 int zbase)
{
    int z = zbase + blockIdx.z;
    const float* W = (z == 0) ? W0 : (z == 1) ? W1 : (z == 2) ? W2 : W3;
    unsigned short* T = (z == 0) ? T0 : (z == 1) ? T1 : (z == 2) ? T2 : T3;
    __shared__ float t[32][33];
    const int tid = threadIdx.x;
    const int k0 = blockIdx.y * 32, n0 = blockIdx.x * 32;
    {
        int r = tid >> 3, c4 = (tid & 7) * 4;
        float4 u = *(const float4*)&W[(size_t)(k0 + r) * DM + n0 + c4];
        t[r][c4 + 0] = u.x; t[r][c4 + 1] = u.y; t[r][c4 + 2] = u.z; t[r][c4 + 3] = u.w;
    }
    __syncthreads();
    {
        int n = tid >> 3, k4 = (tid & 7) * 4;
        ushort4v o;
        o[0] = f2bf(t[k4 + 0][n]); o[1] = f2bf(t[k4 + 1][n]);
        o[2] = f2bf(t[k4 + 2][n]); o[3] = f2bf(t[k4 + 3][n]);
        *(ushort4v*)&T[(size_t)(n0 + n) * DM + k0 + k4] = o;
    }
}

// ---------------------------------------------------------------------------
// Fused Q/K/V projection — r0 sync structure (__syncthreads pair, cvt->stageW
// order, loadPre after B2) with BK 32->64 (iters 32->16) — r18/r19 resubmit.
// r12's BK=64 regression is exonerated: its act prefetch used 128B/lane
// contiguous chunks (lane stride 128B, uncoalesced). Here the act chunk map
// generalizes r0's coalesced pattern: thread t covers 32B chunks {q*256+t},
// row=c>>3, cno=c&7 -> lane stride 32B. [row][64] LDS with attn's proven
// 8-chunk XOR swizzle (slot = cno ^ (row&7)) on cvt-write / gload-source /
// frag-read. MFMA phase = r0's phase executed twice (ks=0,1).
// DO-NOT-TOUCH list (5/5 regressions): 1-barrier dbuf (r10), smaller tiles
// (r11/r15), raw-barrier+counted-vmcnt+sched_barrier (r17).
// (r19: identical resubmission — container acquisition failed before the
// kernel ran; no timing fields in the result JSON.)
// ---------------------------------------------------------------------------
struct ProjArgs {
    const float* act[3];            // queries, keys, values
    const unsigned short* wt[3];    // WqT, WkT, WvT
    const float* bias[3];
    unsigned short* C[3];           // Qh, Kh, Vt
    float oscale[3];
};

__global__ __launch_bounds__(256)
void proj_qkv(ProjArgs pa)
{
    const int z = blockIdx.z;
    const bool vt = (z == 2);
    const int linear = (int)(blockIdx.x + gridDim.x * blockIdx.y);  // 0..255
    int rb, cb;
    if (!vt) { rb = linear & 31; cb = linear >> 5; }   // pin activation row-tile
    else     { cb = linear & 31; rb = linear >> 5; }   // pin values tile
    const int row0 = rb * 128, col0 = cb * 128;

    const float* act = pa.act[z];
    const unsigned short* wt = pa.wt[z];
    const int actBase = vt ? col0 : row0;   // act rows staged (fp32 -> cvt)
    const int wtBase  = vt ? row0 : col0;   // weight rows staged (async bf16)

    __shared__ unsigned short As[128 * 64];  // [row][64], XOR-swizzled chunks
    __shared__ unsigned short Bs[128 * 64];
    unsigned short* convDst  = vt ? Bs : As;
    unsigned short* asyncDst = vt ? As : Bs;

    const int tid = threadIdx.x;
    const int lane = tid & 63, w = tid >> 6;
    const int lane15 = lane & 15, quad = lane >> 4;

    floatx4 acc[2][8] = {};

    // act chunk map: c = q*256 + tid, row = c>>3 = q*32 + (tid>>3), cno = tid&7
    const int arow0 = tid >> 3;
    const int cno   = tid & 7;
    const int acol  = cno * 8;

    float4 pre[8];
    auto loadPre = [&](int kt) {
#pragma unroll
        for (int q = 0; q < 4; ++q) {
            const float* p = &act[(size_t)(actBase + q * 32 + arow0) * DM + kt + acol];
            pre[q * 2]     = *(const float4*)p;
            pre[q * 2 + 1] = *(const float4*)(p + 4);
        }
    };
    auto cvtStore = [&]() {
#pragma unroll
        for (int q = 0; q < 4; ++q) {
            int row  = q * 32 + arow0;
            int slot = cno ^ (row & 7);
            float4 u0 = pre[q * 2], u1 = pre[q * 2 + 1];
            ushort8v o8;
            o8[0] = f2bf(u0.x); o8[1] = f2bf(u0.y); o8[2] = f2bf(u0.z); o8[3] = f2bf(u0.w);
            o8[4] = f2bf(u1.x); o8[5] = f2bf(u1.y); o8[6] = f2bf(u1.z); o8[7] = f2bf(u1.w);
            *(ushort8v*)&convDst[(size_t)(row * 8 + slot) * 8] = o8;
        }
    };
    auto stageW = [&](int kt) {
#pragma unroll
        for (int rr = 0; rr < 4; ++rr) {
            int p = rr * 256 + w * 64 + lane;       // LDS chunk position 0..1023
            int row = p >> 3;
            int gch = (p & 7) ^ (row & 7);          // inverse-swizzled source
            gload_lds16(&wt[(size_t)(wtBase + row) * DM + kt + gch * 8],
                        (char*)asyncDst + (size_t)(rr * 256 + w * 64) * 16);
        }
    };

    loadPre(0);
    for (int kt = 0; kt < DM; kt += 64) {
        __syncthreads();                     // B1: LDS consumers done; pre drained
        cvtStore();
        stageW(kt);
        __syncthreads();                     // B2: drains weight gloads + ds_writes
        if (kt + 64 < DM) loadPre(kt + 64);  // fp32 loads fly during MFMA phase

        // MFMA phase = r0 phase x2 (ks = k 0-31 / 32-63)
#pragma unroll
        for (int ks = 0; ks < 2; ++ks) {
            short8 af[2], bf[8];
#pragma unroll
            for (int i = 0; i < 2; ++i) {
                int row = w * 32 + i * 16 + lane15;
                af[i] = *(const short8*)&As[(size_t)(row * 8 +
                            (((ks << 2) + quad) ^ (row & 7))) * 8];
            }
#pragma unroll
            for (int j = 0; j < 8; ++j) {
                int row = j * 16 + lane15;
                bf[j] = *(const short8*)&Bs[(size_t)(row * 8 +
                            (((ks << 2) + quad) ^ (row & 7))) * 8];
            }
#pragma unroll
            for (int i = 0; i < 2; ++i)
#pragma unroll
                for (int j = 0; j < 8; ++j)
                    acc[i][j] = __builtin_amdgcn_mfma_f32_16x16x32_bf16(
                        af[i], bf[j], acc[i][j], 0, 0, 0);
        }
    }

    const float* bias = pa.bias[z];
    const float os = pa.oscale[z];
    unsigned short* C = pa.C[z];
#pragma unroll
    for (int i = 0; i < 2; ++i) {
#pragma unroll
        for (int j = 0; j < 8; ++j) {
#pragma unroll
            for (int r = 0; r < 4; ++r) {
                int row = row0 + w * 32 + i * 16 + quad * 4 + r;
                int col = col0 + j * 16 + lane15;
                if (!vt) {
                    float v = (acc[i][j][r] + bias[col]) * os;
                    int b = row >> 11, l = row & (SEQ - 1);
                    int h = col >> 6,  e = col & (EH - 1);
                    C[((size_t)(b * NH + h) * SEQ + l) * EH + e] = f2bf(v);
                } else {
                    float v = acc[i][j][r] + bias[row];       // bias by e-row
                    int h = row >> 6,  e = row & (EH - 1);
                    int b = col >> 11, l = col & (SEQ - 1);
                    C[((size_t)(b * NH + h) * EH + e) * SEQ + l] = f2bf(v);
                }
            }
        }
    }
}

// ---------------------------------------------------------------------------
// Output projection — BK=64 (pure-gload staging; r12-round totals suggest
// this variant was ~20us faster than BK=32).
// Tile 128x64, grid (16,32), [row][64] XOR-swizzled, r0 sync structure.
// ---------------------------------------------------------------------------
__global__ __launch_bounds__(256)
void gemm_out(const unsigned short* __restrict__ ctx,
              const unsigned short* __restrict__ WoT,
              const float* __restrict__ bo,
              float* __restrict__ out)
{
    const int linear = (int)(blockIdx.x + gridDim.x * blockIdx.y);  // 0..511
    const int rb = linear & 31, cb = linear >> 5;                   // cb 0..15
    const int row0 = rb * 128, col0 = cb * 64;

    __shared__ unsigned short As[128 * 64];   // 16 KB
    __shared__ unsigned short Bs[64 * 64];    // 8 KB

    const int tid = threadIdx.x;
    const int lane = tid & 63, w = tid >> 6;
    const int lane15 = lane & 15, quad = lane >> 4;

    floatx4 acc[2][4] = {};

    auto stageA = [&](int kt) {
#pragma unroll
        for (int rr = 0; rr < 4; ++rr) {
            int p = rr * 256 + w * 64 + lane;
            int row = p >> 3, gch = (p & 7) ^ (row & 7);
            gload_lds16(&ctx[(size_t)(row0 + row) * DM + kt + gch * 8],
                        (char*)As + (size_t)(rr * 256 + w * 64) * 16);
        }
    };
    auto stageB = [&](int kt) {
#pragma unroll
        for (int rr = 0; rr < 2; ++rr) {
            int p = rr * 256 + w * 64 + lane;
            int row = p >> 3, gch = (p & 7) ^ (row & 7);
            gload_lds16(&WoT[(size_t)(col0 + row) * DM + kt + gch * 8],
                        (char*)Bs + (size_t)(rr * 256 + w * 64) * 16);
        }
    };

    for (int kt = 0; kt < DM; kt += 64) {
        __syncthreads();
        stageA(kt);
        stageB(kt);
        __syncthreads();

#pragma unroll
        for (int ks = 0; ks < 2; ++ks) {
            short8 af[2], bf[4];
#pragma unroll
            for (int i = 0; i < 2; ++i) {
                int row = w * 32 + i * 16 + lane15;
                af[i] = *(const short8*)&As[(size_t)(row * 8 +
                            (((ks << 2) + quad) ^ (row & 7))) * 8];
            }
#pragma unroll
            for (int j = 0; j < 4; ++j) {
                int row = j * 16 + lane15;
                bf[j] = *(const short8*)&Bs[(size_t)(row * 8 +
                            (((ks << 2) + quad) ^ (row & 7))) * 8];
            }
#pragma unroll
            for (int i = 0; i < 2; ++i)
#pragma unroll
                for (int j = 0; j < 4; ++j)
                    acc[i][j] = __builtin_amdgcn_mfma_f32_16x16x32_bf16(
                        af[i], bf[j], acc[i][j], 0, 0, 0);
        }
    }

#pragma unroll
    for (int i = 0; i < 2; ++i)
#pragma unroll
        for (int j = 0; j < 4; ++j)
#pragma unroll
            for (int r = 0; r < 4; ++r) {
                int row = row0 + w * 32 + i * 16 + quad * 4 + r;
                int col = col0 + j * 16 + lane15;
                out[(size_t)row * DM + col] = acc[i][j][r] + bo[col];
            }
}

// ---------------------------------------------------------------------------
// MFMA flash attention — r0 structure + Ps XOR-swizzle (passed r16; neutral
// on time, conflict-free, 2KB less LDS). Unchanged.
// ---------------------------------------------------------------------------
__device__ __forceinline__ void stage_kv(const unsigned short* __restrict__ Kp,
                                         const unsigned short* __restrict__ Vp,
                                         int st, unsigned short* ksb, unsigned short* vsb,
                                         int w, int lane)
{
#pragma unroll
    for (int rr = 0; rr < 2; ++rr) {
        int p = rr * 256 + w * 64 + lane;      // LDS chunk position
        int row = p >> 3;
        int gch = (p & 7) ^ (row & 7);         // swizzled source chunk
        gload_lds16(&Kp[(size_t)(st + row) * EH + gch * 8],
                    ksb + (size_t)(rr * 256 + w * 64) * 8);
        gload_lds16(&Vp[(size_t)row * SEQ + st + gch * 8],
                    vsb + (size_t)(rr * 256 + w * 64) * 8);
    }
}

__global__ __launch_bounds__(256)
void attn_mfma(const unsigned short* __restrict__ Qh,
               const unsigned short* __restrict__ Kh,
               const unsigned short* __restrict__ Vt,
               unsigned short* __restrict__ ctx)
{
    __shared__ unsigned short Ks[2][64 * 64];   // swizzled [s][e]
    __shared__ unsigned short Vs[2][64 * 64];   // swizzled [e][s]
    __shared__ unsigned short Ps[128][64];      // [q_local][s], XOR-swizzled

    const int tid = threadIdx.x;
    const int lane = tid & 63, w = tid >> 6;
    const int lane15 = lane & 15, quad = lane >> 4;

    // (b,h)-pinned swizzle: linear%8 == bh%8 -> one XCD per 4 bh sets
    const int linear = (int)(blockIdx.x + 16 * (blockIdx.y + 16 * blockIdx.z));
    const int bhid = linear & 31;      // 0..31
    const int qt = linear >> 5;        // 0..15
    const int h = bhid & 15, b = bhid >> 4;

    const size_t bh = (size_t)(b * NH + h);
    const unsigned short* Kp = Kh + bh * SEQ * EH;
    const unsigned short* Vp = Vt + bh * EH * SEQ;

    short8 qf[2][2];
    {
        const unsigned short* Qp =
            Qh + (bh * SEQ + (size_t)qt * 128 + w * 32 + lane15) * EH;
#pragma unroll
        for (int ks = 0; ks < 2; ++ks) {
            qf[0][ks] = *(const short8*)(Qp + ks * 32 + quad * 8);
            qf[1][ks] = *(const short8*)(Qp + 16 * EH + ks * 32 + quad * 8);
        }
    }
    short8 ones;
#pragma unroll
    for (int i = 0; i < 8; ++i) ones[i] = (short)0x3F80;   // bf16 1.0

    floatx4 o[2][4] = {};
    floatx4 lacc[2] = {};

    stage_kv(Kp, Vp, 0, Ks[0], Vs[0], w, lane);
    __syncthreads();
    int cur = 0;

    for (int st = 0; st < SEQ; st += 64) {
        int nxt = cur ^ 1;
        if (st + 64 < SEQ)
            stage_kv(Kp, Vp, st + 64, Ks[nxt], Vs[nxt], w, lane);
        const unsigned short* ksb = Ks[cur];
        const unsigned short* vsb = Vs[cur];

        floatx4 sacc[4][2] = {};
#pragma unroll
        for (int ts = 0; ts < 4; ++ts) {
#pragma unroll
            for (int ks = 0; ks < 2; ++ks) {
                short8 kf = *(const short8*)&ksb[((ts * 16 + lane15) << 6) +
                                                 ((((ks << 2) + quad) ^ (lane15 & 7)) << 3)];
                sacc[ts][0] = __builtin_amdgcn_mfma_f32_16x16x32_bf16(kf, qf[0][ks], sacc[ts][0], 0, 0, 0);
                sacc[ts][1] = __builtin_amdgcn_mfma_f32_16x16x32_bf16(kf, qf[1][ks], sacc[ts][1], 0, 0, 0);
            }
        }

        // P = exp2(S'); pack 4 consecutive-s bf16 -> one 8B write per tile,
        // at XOR-swizzled chunk: phys = ((ts*2+(quad>>1)) ^ (row&7))*8 + (quad&1)*4
#pragma unroll
        for (int ts = 0; ts < 4; ++ts)
#pragma unroll
            for (int nq = 0; nq < 2; ++nq) {
                unsigned int u0 = __float_as_uint(__builtin_amdgcn_exp2f(sacc[ts][nq][0])) + 0x8000u;
                unsigned int u1 = __float_as_uint(__builtin_amdgcn_exp2f(sacc[ts][nq][1])) + 0x8000u;
                unsigned int u2 = __float_as_uint(__builtin_amdgcn_exp2f(sacc[ts][nq][2])) + 0x8000u;
                unsigned int u3 = __float_as_uint(__builtin_amdgcn_exp2f(sacc[ts][nq][3])) + 0x8000u;
                uint2 pk;
                pk.x = (u0 >> 16) | (u1 & 0xFFFF0000u);
                pk.y = (u2 >> 16) | (u3 & 0xFFFF0000u);
                *(uint2*)&Ps[w * 32 + nq * 16 + lane15]
                            [(((ts * 2 + (quad >> 1)) ^ (lane15 & 7)) << 3) + ((quad & 1) << 2)] = pk;
            }

        // O += P @ V ; l += P @ 1   (Ps rows wave-local: no barrier needed)
#pragma unroll
        for (int ks = 0; ks < 2; ++ks) {
            short8 pf[2];
#pragma unroll
            for (int mt = 0; mt < 2; ++mt) {
                pf[mt] = *(const short8*)&Ps[w * 32 + mt * 16 + lane15]
                                            [((((ks << 2) + quad) ^ (lane15 & 7)) << 3)];
                lacc[mt] = __builtin_amdgcn_mfma_f32_16x16x32_bf16(pf[mt], ones, lacc[mt], 0, 0, 0);
            }
#pragma unroll
            for (int t2 = 0; t2 < 4; ++t2) {
                short8 vf = *(const short8*)&vsb[((t2 * 16 + lane15) << 6) +
                                                 ((((ks << 2) + quad) ^ (lane15 & 7)) << 3)];
                o[0][t2] = __builtin_amdgcn_mfma_f32_16x16x32_bf16(pf[0], vf, o[0][t2], 0, 0, 0);
                o[1][t2] = __builtin_amdgcn_mfma_f32_16x16x32_bf16(pf[1], vf, o[1][t2], 0, 0, 0);
            }
        }
        __syncthreads();
        cur = nxt;
    }

#pragma unroll
    for (int mt = 0; mt < 2; ++mt) {
        float inv[4];
#pragma unroll
        for (int r = 0; r < 4; ++r) inv[r] = 1.0f / lacc[mt][r];
#pragma unroll
        for (int t2 = 0; t2 < 4; ++t2)
#pragma unroll
            for (int r = 0; r < 4; ++r) {
                int q = qt * 128 + w * 32 + mt * 16 + quad * 4 + r;
                int col = h * EH + t2 * 16 + lane15;
                ctx[((size_t)(b * SEQ + q)) * DM + col] = f2bf(o[mt][t2][r] * inv[r]);
            }
    }
}

extern "C" void kernel_launch(void* const* d_in, const int* in_sizes, int n_in,
                              void* d_out, int out_size, void* d_ws, size_t ws_size,
                              hipStream_t stream)
{
    const float* queries = (const float*)d_in[0];
    const float* keys    = (const float*)d_in[1];
    const float* values  = (const float*)d_in[2];
    const float* Wq = (const float*)d_in[3];
    const float* bq = (const float*)d_in[4];
    const float* Wk = (const float*)d_in[5];
    const float* bk = (const float*)d_in[6];
    const float* Wv = (const float*)d_in[7];
    const float* bv = (const float*)d_in[8];
    const float* Wo = (const float*)d_in[9];
    const float* bo = (const float*)d_in[10];
    float* out = (float*)d_out;

    // 32 MB workspace (ushort elems):
    //   [0,4M)   Qh    (WoT overlays after attn)
    //   [4M,8M)  Kh
    //   [8M,12M) Vt
    //   [12M,16M) ctx  (WqT/WkT/WvT live here until attn overwrites)
    unsigned short* ws = (unsigned short*)d_ws;
    const size_t MAT = (size_t)MROWS * DM;   // 4M elems
    const size_t WSZ = (size_t)DM * DM;      // 1M elems
    unsigned short* Qhp = ws;
    unsigned short* Khp = ws + MAT;
    unsigned short* Vtp = ws + 2 * MAT;
    unsigned short* ctx = ws + 3 * MAT;
    unsigned short* WqT = ctx;               // dead once attn writes ctx
    unsigned short* WkT = ctx + WSZ;
    unsigned short* WvT = ctx + 2 * WSZ;
    unsigned short* WoT = ws;                // overlays Qh after attn

    // 1/sqrt(EH) * log2(e): exp2(S') == exp(S/8)
    const float qscale = 0.125f * 1.44269504088896f;

    // 1. weight transposes Wq/Wk/Wv
    transpose_w<<<dim3(DM / 32, DM / 32, 3), 256, 0, stream>>>(
        Wq, Wk, Wv, Wo, WqT, WkT, WvT, WoT, 0);

    // 2. fused Q/K/V projections (BK=64, coalesced act chunks, r0 sync)
    ProjArgs pa;
    pa.act[0] = queries; pa.act[1] = keys; pa.act[2] = values;
    pa.wt[0] = WqT;      pa.wt[1] = WkT;   pa.wt[2] = WvT;
    pa.bias[0] = bq;     pa.bias[1] = bk;  pa.bias[2] = bv;
    pa.C[0] = Qhp;       pa.C[1] = Khp;    pa.C[2] = Vtp;
    pa.oscale[0] = qscale; pa.oscale[1] = 1.f; pa.oscale[2] = 1.f;
    proj_qkv<<<dim3(8, 32, 3), 256, 0, stream>>>(pa);

    // 3. attention -> ctx
    attn_mfma<<<dim3(SEQ / 128, NH, BATCH), 256, 0, stream>>>(Qhp, Khp, Vtp, ctx);

    // 4. Wo transpose into dead Qh region
    transpose_w<<<dim3(DM / 32, DM / 32, 1), 256, 0, stream>>>(
        Wq, Wk, Wv, Wo, WqT, WkT, WvT, WoT, 3);

    // 5. output projection (BK=64)
    gemm_out<<<dim3(16, 32), 256, 0, stream>>>(ctx, WoT, bo, out);
}

// Round 11
// 226.765 us; speedup vs baseline: 1.1967x; 1.0520x over previous
//
#include <hip/hip_runtime.h>
#include <hip/hip_bf16.h>
#include <stdint.h>

// B=2, L=S=2048, D_MODEL=1024, H=16, E=64. Inputs/outputs fp32; intermediates bf16.
#define BATCH 2
#define SEQ   2048
#define DM    1024
#define NH    16
#define EH    64
#define MROWS (BATCH*SEQ)   // 4096

typedef __attribute__((ext_vector_type(8))) short  short8;   // MFMA A/B frag (8 bf16)
typedef __attribute__((ext_vector_type(4))) float  floatx4;  // MFMA C/D frag
typedef __attribute__((ext_vector_type(8))) unsigned short ushort8v;
typedef __attribute__((ext_vector_type(4))) unsigned short ushort4v;

// Half-up rounding (2 VALU): differs from RNE only on exact 0x8000 ties (p~2^-16).
__device__ __forceinline__ unsigned short f2bf(float f) {
    return (unsigned short)((__float_as_uint(f) + 0x8000u) >> 16);
}

__device__ __forceinline__ void gload_lds16(const void* g, void* l) {
    // async global->LDS, 16B/lane; LDS dest = wave-uniform base + lane*16
    __builtin_amdgcn_global_load_lds(
        (const __attribute__((address_space(1))) unsigned int*)g,
        (__attribute__((address_space(3))) unsigned int*)l, 16, 0, 0);
}

// ---------------------------------------------------------------------------
// Transpose+convert: W [K][N] fp32 -> WT [N][K] bf16. 32x32 LDS tiles.
// ---------------------------------------------------------------------------
__global__ __launch_bounds__(256)
void transpose_w(const float* __restrict__ W0, const float* __restrict__ W1,
                 const float* __restrict__ W2, const float* __restrict__ W3,
                 unsigned short* __restrict__ T0, unsigned short* __restrict__ T1,
                 unsigned short* __restrict__ T2, unsigned short* __restrict__ T3,
                 int zbase)
{
    int z = zbase + blockIdx.z;
    const float* W = (z == 0) ? W0 : (z == 1) ? W1 : (z == 2) ? W2 : W3;
    unsigned short* T = (z == 0) ? T0 : (z == 1) ? T1 : (z == 2) ? T2 : T3;
    __shared__ float t[32][33];
    const int tid = threadIdx.x;
    const int k0 = blockIdx.y * 32, n0 = blockIdx.x * 32;
    {
        int r = tid >> 3, c4 = (tid & 7) * 4;
        float4 u = *(const float4*)&W[(size_t)(k0 + r) * DM + n0 + c4];
        t[r][c4 + 0] = u.x; t[r][c4 + 1] = u.y; t[r][c4 + 2] = u.z; t[r][c4 + 3] = u.w;
    }
    __syncthreads();
    {
        int n = tid >> 3, k4 = (tid & 7) * 4;
        ushort4v o;
        o[0] = f2bf(t[k4 + 0][n]); o[1] = f2bf(t[k4 + 1][n]);
        o[2] = f2bf(t[k4 + 2][n]); o[3] = f2bf(t[k4 + 3][n]);
        *(ushort4v*)&T[(size_t)(n0 + n) * DM + k0 + k4] = o;
    }
}

// ---------------------------------------------------------------------------
// Fused Q/K/V projection — r16-measured 62us version (r0 structure + neutral
// conflict-free swizzle). FINAL for proj: measured local optimum in tile-M
// (r15), tile-N (r11), BK (r12/r18), sync structure (r10/r17) — every
// deviation regressed; phase cost ~ fixed_drain + k*(staged bytes/iter).
// Grid (8,32,3), tile 128x128, BK=32, 2-barrier phases, reg-prefetch pre[4],
// wave tile 32x128 acc[2][8]. XCD-pinned swizzle (FETCH 49MB).
// ---------------------------------------------------------------------------
struct ProjArgs {
    const float* act[3];            // queries, keys, values
    const unsigned short* wt[3];    // WqT, WkT, WvT
    const float* bias[3];
    unsigned short* C[3];           // Qh, Kh, Vt
    float oscale[3];
};

__global__ __launch_bounds__(256)
void proj_qkv(ProjArgs pa)
{
    const int z = blockIdx.z;
    const bool vt = (z == 2);
    const int linear = (int)(blockIdx.x + gridDim.x * blockIdx.y);  // 0..255
    int rb, cb;
    if (!vt) { rb = linear & 31; cb = linear >> 5; }   // pin activation row-tile
    else     { cb = linear & 31; rb = linear >> 5; }   // pin values tile
    const int row0 = rb * 128, col0 = cb * 128;

    const float* act = pa.act[z];
    const unsigned short* wt = pa.wt[z];
    const int actBase = vt ? col0 : row0;   // act rows staged (fp32 -> cvt)
    const int wtBase  = vt ? row0 : col0;   // weight rows staged (async bf16)

    __shared__ unsigned short As[128 * 32];  // [row][32], 64B rows
    __shared__ unsigned short Bs[128 * 32];
    unsigned short* convDst  = vt ? Bs : As;
    unsigned short* asyncDst = vt ? As : Bs;

    const int tid = threadIdx.x;
    const int lane = tid & 63, w = tid >> 6;
    const int lane15 = lane & 15, quad = lane >> 4;

    floatx4 acc[2][8] = {};

    // per-thread fp32 prefetch regs: rows tid>>2 and 64+(tid>>2), 8 fp32 each
    float4 pre[4];
    {
        const float* p0 = &act[(size_t)(actBase + (tid >> 2)) * DM + ((tid & 3) * 8)];
        const float* p1 = &act[(size_t)(actBase + ((256 + tid) >> 2)) * DM + ((tid & 3) * 8)];
        pre[0] = *(const float4*)p0; pre[1] = *(const float4*)(p0 + 4);
        pre[2] = *(const float4*)p1; pre[3] = *(const float4*)(p1 + 4);
    }

    // swizzled chunk slot for this thread's cvt rows (same for both rr:
    // row_rr1 = 64 + row_rr0, (64>>1)&3 == 0)
    const int cp = (tid & 3) ^ (((tid >> 2) >> 1) & 3);
    const int sw = (lane15 >> 1) & 3;

    for (int kt = 0; kt < DM; kt += 32) {
        __syncthreads();                     // LDS consumers done; drains prefetch
        // cvt regs -> LDS (swizzled slot)
#pragma unroll
        for (int rr = 0; rr < 2; ++rr) {
            int row = rr * 64 + (tid >> 2);
            ushort8v o8;
            float4 u0 = pre[rr * 2], u1 = pre[rr * 2 + 1];
            o8[0] = f2bf(u0.x); o8[1] = f2bf(u0.y); o8[2] = f2bf(u0.z); o8[3] = f2bf(u0.w);
            o8[4] = f2bf(u1.x); o8[5] = f2bf(u1.y); o8[6] = f2bf(u1.z); o8[7] = f2bf(u1.w);
            *(ushort8v*)&convDst[(size_t)(row * 4 + cp) * 8] = o8;
        }
        // async bf16 weight staging: linear LDS dest, inverse-swizzled source
#pragma unroll
        for (int rr = 0; rr < 2; ++rr) {
            int c = rr * 256 + w * 64 + lane;
            int row = c >> 2;
            int gch = (c & 3) ^ ((row >> 1) & 3);
            gload_lds16(&wt[(size_t)(wtBase + row) * DM + kt + gch * 8],
                        (char*)asyncDst + (size_t)(rr * 256 + w * 64) * 16);
        }
        __syncthreads();                     // drains async weight loads only

        // issue NEXT k-tile fp32 loads (land during MFMA below)
        if (kt + 32 < DM) {
            int kn = kt + 32;
            const float* p0 = &act[(size_t)(actBase + (tid >> 2)) * DM + kn + ((tid & 3) * 8)];
            const float* p1 = &act[(size_t)(actBase + ((256 + tid) >> 2)) * DM + kn + ((tid & 3) * 8)];
            pre[0] = *(const float4*)p0; pre[1] = *(const float4*)(p0 + 4);
            pre[2] = *(const float4*)p1; pre[3] = *(const float4*)(p1 + 4);
        }

        short8 af[2], bf[8];
#pragma unroll
        for (int i = 0; i < 2; ++i)
            af[i] = *(const short8*)&As[(w * 32 + i * 16 + lane15) * 32 + ((quad ^ sw) << 3)];
#pragma unroll
        for (int j = 0; j < 8; ++j)
            bf[j] = *(const short8*)&Bs[(j * 16 + lane15) * 32 + ((quad ^ sw) << 3)];
#pragma unroll
        for (int i = 0; i < 2; ++i)
#pragma unroll
            for (int j = 0; j < 8; ++j)
                acc[i][j] = __builtin_amdgcn_mfma_f32_16x16x32_bf16(af[i], bf[j], acc[i][j], 0, 0, 0);
    }

    const float* bias = pa.bias[z];
    const float os = pa.oscale[z];
    unsigned short* C = pa.C[z];
#pragma unroll
    for (int i = 0; i < 2; ++i) {
#pragma unroll
        for (int j = 0; j < 8; ++j) {
#pragma unroll
            for (int r = 0; r < 4; ++r) {
                int row = row0 + w * 32 + i * 16 + quad * 4 + r;
                int col = col0 + j * 16 + lane15;
                if (!vt) {
                    float v = (acc[i][j][r] + bias[col]) * os;
                    int b = row >> 11, l = row & (SEQ - 1);
                    int h = col >> 6,  e = col & (EH - 1);
                    C[((size_t)(b * NH + h) * SEQ + l) * EH + e] = f2bf(v);
                } else {
                    float v = acc[i][j][r] + bias[row];       // bias by e-row
                    int h = row >> 6,  e = row & (EH - 1);
                    int b = col >> 11, l = col & (SEQ - 1);
                    C[((size_t)(b * NH + h) * EH + e) * SEQ + l] = f2bf(v);
                }
            }
        }
    }
}

// ---------------------------------------------------------------------------
// Output projection — BK=64 (kept from r18: pure-gload staging, no cvt path,
// passed twice; r18 non-proj total 160 vs r16's 166).
// Tile 128x64, grid (16,32), [row][64] XOR-swizzled, r0 sync structure.
// ---------------------------------------------------------------------------
__global__ __launch_bounds__(256)
void gemm_out(const unsigned short* __restrict__ ctx,
              const unsigned short* __restrict__ WoT,
              const float* __restrict__ bo,
              float* __restrict__ out)
{
    const int linear = (int)(blockIdx.x + gridDim.x * blockIdx.y);  // 0..511
    const int rb = linear & 31, cb = linear >> 5;                   // cb 0..15
    const int row0 = rb * 128, col0 = cb * 64;

    __shared__ unsigned short As[128 * 64];   // 16 KB
    __shared__ unsigned short Bs[64 * 64];    // 8 KB

    const int tid = threadIdx.x;
    const int lane = tid & 63, w = tid >> 6;
    const int lane15 = lane & 15, quad = lane >> 4;

    floatx4 acc[2][4] = {};

    auto stageA = [&](int kt) {
#pragma unroll
        for (int rr = 0; rr < 4; ++rr) {
            int p = rr * 256 + w * 64 + lane;
            int row = p >> 3, gch = (p & 7) ^ (row & 7);
            gload_lds16(&ctx[(size_t)(row0 + row) * DM + kt + gch * 8],
                        (char*)As + (size_t)(rr * 256 + w * 64) * 16);
        }
    };
    auto stageB = [&](int kt) {
#pragma unroll
        for (int rr = 0; rr < 2; ++rr) {
            int p = rr * 256 + w * 64 + lane;
            int row = p >> 3, gch = (p & 7) ^ (row & 7);
            gload_lds16(&WoT[(size_t)(col0 + row) * DM + kt + gch * 8],
                        (char*)Bs + (size_t)(rr * 256 + w * 64) * 16);
        }
    };

    for (int kt = 0; kt < DM; kt += 64) {
        __syncthreads();
        stageA(kt);
        stageB(kt);
        __syncthreads();

#pragma unroll
        for (int ks = 0; ks < 2; ++ks) {
            short8 af[2], bf[4];
#pragma unroll
            for (int i = 0; i < 2; ++i) {
                int row = w * 32 + i * 16 + lane15;
                af[i] = *(const short8*)&As[(size_t)(row * 8 +
                            (((ks << 2) + quad) ^ (row & 7))) * 8];
            }
#pragma unroll
            for (int j = 0; j < 4; ++j) {
                int row = j * 16 + lane15;
                bf[j] = *(const short8*)&Bs[(size_t)(row * 8 +
                            (((ks << 2) + quad) ^ (row & 7))) * 8];
            }
#pragma unroll
            for (int i = 0; i < 2; ++i)
#pragma unroll
                for (int j = 0; j < 4; ++j)
                    acc[i][j] = __builtin_amdgcn_mfma_f32_16x16x32_bf16(
                        af[i], bf[j], acc[i][j], 0, 0, 0);
        }
    }

#pragma unroll
    for (int i = 0; i < 2; ++i)
#pragma unroll
        for (int j = 0; j < 4; ++j)
#pragma unroll
            for (int r = 0; r < 4; ++r) {
                int row = row0 + w * 32 + i * 16 + quad * 4 + r;
                int col = col0 + j * 16 + lane15;
                out[(size_t)row * DM + col] = acc[i][j][r] + bo[col];
            }
}

// ---------------------------------------------------------------------------
// MFMA flash attention — r16 structure + T5 s_setprio around MFMA clusters.
// attn runs 2 independent blocks/CU (no inter-block sync) — the regime where
// setprio measured +4-7% (m191): boosts the MFMA-issuing wave's priority over
// other waves' staging/VALU. No sync-structure change (rule: 6/6 structural
// edits regressed). Ps XOR-swizzled, K/V async dbuf, 1 barrier/iter.
// ---------------------------------------------------------------------------
__device__ __forceinline__ void stage_kv(const unsigned short* __restrict__ Kp,
                                         const unsigned short* __restrict__ Vp,
                                         int st, unsigned short* ksb, unsigned short* vsb,
                                         int w, int lane)
{
#pragma unroll
    for (int rr = 0; rr < 2; ++rr) {
        int p = rr * 256 + w * 64 + lane;      // LDS chunk position
        int row = p >> 3;
        int gch = (p & 7) ^ (row & 7);         // swizzled source chunk
        gload_lds16(&Kp[(size_t)(st + row) * EH + gch * 8],
                    ksb + (size_t)(rr * 256 + w * 64) * 8);
        gload_lds16(&Vp[(size_t)row * SEQ + st + gch * 8],
                    vsb + (size_t)(rr * 256 + w * 64) * 8);
    }
}

__global__ __launch_bounds__(256)
void attn_mfma(const unsigned short* __restrict__ Qh,
               const unsigned short* __restrict__ Kh,
               const unsigned short* __restrict__ Vt,
               unsigned short* __restrict__ ctx)
{
    __shared__ unsigned short Ks[2][64 * 64];   // swizzled [s][e]
    __shared__ unsigned short Vs[2][64 * 64];   // swizzled [e][s]
    __shared__ unsigned short Ps[128][64];      // [q_local][s], XOR-swizzled

    const int tid = threadIdx.x;
    const int lane = tid & 63, w = tid >> 6;
    const int lane15 = lane & 15, quad = lane >> 4;

    // (b,h)-pinned swizzle: linear%8 == bh%8 -> one XCD per 4 bh sets
    const int linear = (int)(blockIdx.x + 16 * (blockIdx.y + 16 * blockIdx.z));
    const int bhid = linear & 31;      // 0..31
    const int qt = linear >> 5;        // 0..15
    const int h = bhid & 15, b = bhid >> 4;

    const size_t bh = (size_t)(b * NH + h);
    const unsigned short* Kp = Kh + bh * SEQ * EH;
    const unsigned short* Vp = Vt + bh * EH * SEQ;

    short8 qf[2][2];
    {
        const unsigned short* Qp =
            Qh + (bh * SEQ + (size_t)qt * 128 + w * 32 + lane15) * EH;
#pragma unroll
        for (int ks = 0; ks < 2; ++ks) {
            qf[0][ks] = *(const short8*)(Qp + ks * 32 + quad * 8);
            qf[1][ks] = *(const short8*)(Qp + 16 * EH + ks * 32 + quad * 8);
        }
    }
    short8 ones;
#pragma unroll
    for (int i = 0; i < 8; ++i) ones[i] = (short)0x3F80;   // bf16 1.0

    floatx4 o[2][4] = {};
    floatx4 lacc[2] = {};

    stage_kv(Kp, Vp, 0, Ks[0], Vs[0], w, lane);
    __syncthreads();
    int cur = 0;

    for (int st = 0; st < SEQ; st += 64) {
        int nxt = cur ^ 1;
        if (st + 64 < SEQ)
            stage_kv(Kp, Vp, st + 64, Ks[nxt], Vs[nxt], w, lane);
        const unsigned short* ksb = Ks[cur];
        const unsigned short* vsb = Vs[cur];

        floatx4 sacc[4][2] = {};
        __builtin_amdgcn_s_setprio(1);
#pragma unroll
        for (int ts = 0; ts < 4; ++ts) {
#pragma unroll
            for (int ks = 0; ks < 2; ++ks) {
                short8 kf = *(const short8*)&ksb[((ts * 16 + lane15) << 6) +
                                                 ((((ks << 2) + quad) ^ (lane15 & 7)) << 3)];
                sacc[ts][0] = __builtin_amdgcn_mfma_f32_16x16x32_bf16(kf, qf[0][ks], sacc[ts][0], 0, 0, 0);
                sacc[ts][1] = __builtin_amdgcn_mfma_f32_16x16x32_bf16(kf, qf[1][ks], sacc[ts][1], 0, 0, 0);
            }
        }
        __builtin_amdgcn_s_setprio(0);

        // P = exp2(S'); pack 4 consecutive-s bf16 -> one 8B write per tile,
        // at XOR-swizzled chunk: phys = ((ts*2+(quad>>1)) ^ (row&7))*8 + (quad&1)*4
#pragma unroll
        for (int ts = 0; ts < 4; ++ts)
#pragma unroll
            for (int nq = 0; nq < 2; ++nq) {
                unsigned int u0 = __float_as_uint(__builtin_amdgcn_exp2f(sacc[ts][nq][0])) + 0x8000u;
                unsigned int u1 = __float_as_uint(__builtin_amdgcn_exp2f(sacc[ts][nq][1])) + 0x8000u;
                unsigned int u2 = __float_as_uint(__builtin_amdgcn_exp2f(sacc[ts][nq][2])) + 0x8000u;
                unsigned int u3 = __float_as_uint(__builtin_amdgcn_exp2f(sacc[ts][nq][3])) + 0x8000u;
                uint2 pk;
                pk.x = (u0 >> 16) | (u1 & 0xFFFF0000u);
                pk.y = (u2 >> 16) | (u3 & 0xFFFF0000u);
                *(uint2*)&Ps[w * 32 + nq * 16 + lane15]
                            [(((ts * 2 + (quad >> 1)) ^ (lane15 & 7)) << 3) + ((quad & 1) << 2)] = pk;
            }

        // O += P @ V ; l += P @ 1   (Ps rows wave-local: no barrier needed)
        __builtin_amdgcn_s_setprio(1);
#pragma unroll
        for (int ks = 0; ks < 2; ++ks) {
            short8 pf[2];
#pragma unroll
            for (int mt = 0; mt < 2; ++mt) {
                pf[mt] = *(const short8*)&Ps[w * 32 + mt * 16 + lane15]
                                            [((((ks << 2) + quad) ^ (lane15 & 7)) << 3)];
                lacc[mt] = __builtin_amdgcn_mfma_f32_16x16x32_bf16(pf[mt], ones, lacc[mt], 0, 0, 0);
            }
#pragma unroll
            for (int t2 = 0; t2 < 4; ++t2) {
                short8 vf = *(const short8*)&vsb[((t2 * 16 + lane15) << 6) +
                                                 ((((ks << 2) + quad) ^ (lane15 & 7)) << 3)];
                o[0][t2] = __builtin_amdgcn_mfma_f32_16x16x32_bf16(pf[0], vf, o[0][t2], 0, 0, 0);
                o[1][t2] = __builtin_amdgcn_mfma_f32_16x16x32_bf16(pf[1], vf, o[1][t2], 0, 0, 0);
            }
        }
        __builtin_amdgcn_s_setprio(0);
        __syncthreads();
        cur = nxt;
    }

#pragma unroll
    for (int mt = 0; mt < 2; ++mt) {
        float inv[4];
#pragma unroll
        for (int r = 0; r < 4; ++r) inv[r] = 1.0f / lacc[mt][r];
#pragma unroll
        for (int t2 = 0; t2 < 4; ++t2)
#pragma unroll
            for (int r = 0; r < 4; ++r) {
                int q = qt * 128 + w * 32 + mt * 16 + quad * 4 + r;
                int col = h * EH + t2 * 16 + lane15;
                ctx[((size_t)(b * SEQ + q)) * DM + col] = f2bf(o[mt][t2][r] * inv[r]);
            }
    }
}

extern "C" void kernel_launch(void* const* d_in, const int* in_sizes, int n_in,
                              void* d_out, int out_size, void* d_ws, size_t ws_size,
                              hipStream_t stream)
{
    const float* queries = (const float*)d_in[0];
    const float* keys    = (const float*)d_in[1];
    const float* values  = (const float*)d_in[2];
    const float* Wq = (const float*)d_in[3];
    const float* bq = (const float*)d_in[4];
    const float* Wk = (const float*)d_in[5];
    const float* bk = (const float*)d_in[6];
    const float* Wv = (const float*)d_in[7];
    const float* bv = (const float*)d_in[8];
    const float* Wo = (const float*)d_in[9];
    const float* bo = (const float*)d_in[10];
    float* out = (float*)d_out;

    // 32 MB workspace (ushort elems):
    //   [0,4M)   Qh    (WoT overlays after attn)
    //   [4M,8M)  Kh
    //   [8M,12M) Vt
    //   [12M,16M) ctx  (WqT/WkT/WvT live here until attn overwrites)
    unsigned short* ws = (unsigned short*)d_ws;
    const size_t MAT = (size_t)MROWS * DM;   // 4M elems
    const size_t WSZ = (size_t)DM * DM;      // 1M elems
    unsigned short* Qhp = ws;
    unsigned short* Khp = ws + MAT;
    unsigned short* Vtp = ws + 2 * MAT;
    unsigned short* ctx = ws + 3 * MAT;
    unsigned short* WqT = ctx;               // dead once attn writes ctx
    unsigned short* WkT = ctx + WSZ;
    unsigned short* WvT = ctx + 2 * WSZ;
    unsigned short* WoT = ws;                // overlays Qh after attn

    // 1/sqrt(EH) * log2(e): exp2(S') == exp(S/8)
    const float qscale = 0.125f * 1.44269504088896f;

    // 1. weight transposes Wq/Wk/Wv
    transpose_w<<<dim3(DM / 32, DM / 32, 3), 256, 0, stream>>>(
        Wq, Wk, Wv, Wo, WqT, WkT, WvT, WoT, 0);

    // 2. fused Q/K/V projections (r16-measured 62us version)
    ProjArgs pa;
    pa.act[0] = queries; pa.act[1] = keys; pa.act[2] = values;
    pa.wt[0] = WqT;      pa.wt[1] = WkT;   pa.wt[2] = WvT;
    pa.bias[0] = bq;     pa.bias[1] = bk;  pa.bias[2] = bv;
    pa.C[0] = Qhp;       pa.C[1] = Khp;    pa.C[2] = Vtp;
    pa.oscale[0] = qscale; pa.oscale[1] = 1.f; pa.oscale[2] = 1.f;
    proj_qkv<<<dim3(8, 32, 3), 256, 0, stream>>>(pa);

    // 3. attention -> ctx (+ setprio)
    attn_mfma<<<dim3(SEQ / 128, NH, BATCH), 256, 0, stream>>>(Qhp, Khp, Vtp, ctx);

    // 4. Wo transpose into dead Qh region
    transpose_w<<<dim3(DM / 32, DM / 32, 1), 256, 0, stream>>>(
        Wq, Wk, Wv, Wo, WqT, WkT, WvT, WoT, 3);

    // 5. output projection (BK=64)
    gemm_out<<<dim3(16, 32), 256, 0, stream>>>(ctx, WoT, bo, out);
}